// Round 2
// baseline (3588.837 us; speedup 1.0000x reference)
//
#include <hip/hip_runtime.h>

#define NN 50000
#define NE 800000
#define PD 128

typedef __attribute__((ext_vector_type(8))) short bf16x8;
typedef __attribute__((ext_vector_type(4))) float f32x4;

__device__ __forceinline__ float bf2f(unsigned short h) {
  union { unsigned u; float f; } v; v.u = ((unsigned)h) << 16; return v.f;
}
__device__ __forceinline__ unsigned short f2bf(float f) {
  union { float f; unsigned u; } v; v.f = f;
  unsigned r = (v.u + 0x7FFFu + ((v.u >> 16) & 1u)) >> 16;
  return (unsigned short)r;
}
// order-preserving float<->uint encode for atomicMax-based segment max
__device__ __forceinline__ unsigned encf(float f) {
  union { float f; unsigned u; } v; v.f = f;
  return (v.u & 0x80000000u) ? ~v.u : (v.u | 0x80000000u);
}
__device__ __forceinline__ float decf(unsigned k) {
  union { unsigned u; float f; } v;
  v.u = (k & 0x80000000u) ? (k & 0x7FFFFFFFu) : ~k;
  return v.f;
}

// ---------------------------------------------------------------------------
// C[M,128] = A[M,K] @ B[K,128] (+ bias). A: fp32 (A_F32=1) or bf16; B/bias fp32.
// Out: fp32 (OUT_F32=1) or bf16. fp32->bf16 conversion happens during LDS
// staging; MFMA = 16x16x32 bf16, fp32 accumulate.
// Block = 256 thr = 4 waves; tile 64(M) x 128(N); K-chunks of 32.
template <int A_F32, int OUT_F32>
__global__ __launch_bounds__(256) void gemm_k(
    const void* __restrict__ Av, const float* __restrict__ B,
    const float* __restrict__ bias, void* __restrict__ Cv, int M, int K) {
  __shared__ __align__(16) unsigned short As[64 * 40];
  __shared__ __align__(16) unsigned short Bs[32 * 132];
  int tid = threadIdx.x;
  int wave = tid >> 6, lane = tid & 63;
  int m16 = lane & 15, quad = lane >> 4;
  int row0 = blockIdx.x * 64;

  f32x4 acc[8];
#pragma unroll
  for (int t = 0; t < 8; ++t) acc[t] = (f32x4){0.f, 0.f, 0.f, 0.f};

  int nchunks = (K + 31) / 32;
  for (int ch = 0; ch < nchunks; ++ch) {
    int k0 = ch * 32;
    // stage A: 64 rows x 32 k (4-element granules; K%4==0 for all our K)
    for (int s = tid; s < 512; s += 256) {
      int r = s >> 3, c4 = s & 7;
      int gr = row0 + r, gk = k0 + c4 * 4;
      ushort4 v = {0, 0, 0, 0};
      if (gr < M && gk < K) {
        if (A_F32) {
          const float* A = (const float*)Av;
          float4 f = *(const float4*)(A + (size_t)gr * K + gk);
          v.x = f2bf(f.x); v.y = f2bf(f.y); v.z = f2bf(f.z); v.w = f2bf(f.w);
        } else {
          const unsigned short* A = (const unsigned short*)Av;
          v = *(const ushort4*)(A + (size_t)gr * K + gk);
        }
      }
      *(ushort4*)(As + r * 40 + c4 * 4) = v;
    }
    // stage B: 32 k x 128 n (fp32 -> bf16)
    for (int s = tid; s < 1024; s += 256) {
      int kk = s >> 5, c4 = s & 31;
      int gk = k0 + kk;
      ushort4 v = {0, 0, 0, 0};
      if (gk < K) {
        float4 f = *(const float4*)(B + (size_t)gk * PD + c4 * 4);
        v.x = f2bf(f.x); v.y = f2bf(f.y); v.z = f2bf(f.z); v.w = f2bf(f.w);
      }
      *(ushort4*)(Bs + kk * 132 + c4 * 4) = v;
    }
    __syncthreads();

    // A-frag: lane holds A[m=lane&15][k=quad*8+j]  (one ds_read_b128)
    bf16x8 a = *(const bf16x8*)(As + (wave * 16 + m16) * 40 + quad * 8);
#pragma unroll
    for (int t = 0; t < 8; ++t) {
      // B-frag: lane holds B[k=quad*8+j][n=lane&15]
      bf16x8 b;
#pragma unroll
      for (int j = 0; j < 8; ++j)
        b[j] = (short)Bs[(quad * 8 + j) * 132 + t * 16 + m16];
      acc[t] = __builtin_amdgcn_mfma_f32_16x16x32_bf16(a, b, acc[t], 0, 0, 0);
    }
    __syncthreads();
  }

  // epilogue: C/D layout col=lane&15, row=quad*4+r
#pragma unroll
  for (int t = 0; t < 8; ++t) {
    int col = t * 16 + m16;
    float bv = bias ? bias[col] : 0.f;
#pragma unroll
    for (int r = 0; r < 4; ++r) {
      int row = row0 + wave * 16 + quad * 4 + r;
      if (row < M) {
        float v = acc[t][r] + bv;
        if (OUT_F32) ((float*)Cv)[(size_t)row * PD + col] = v;
        else ((unsigned short*)Cv)[(size_t)row * PD + col] = f2bf(v);
      }
    }
  }
}

// ---------------------------------------------------------------------------
__global__ __launch_bounds__(256) void init_md(
    float* __restrict__ den, unsigned* __restrict__ menc) {
  int i = blockIdx.x * 256 + threadIdx.x;
  if (i < NN * 4) { den[i] = 0.f; menc[i] = 0x007FFFFFu; }  // enc(-inf)
}

__global__ __launch_bounds__(256) void init_accum(float* __restrict__ accum) {
  int i = blockIdx.x * 256 + threadIdx.x;
  accum[i] = 0.f;
}

// ---------------------------------------------------------------------------
// pass 1: e[eid][h] = sum_c att[h,c]*lrelu(xl[src,h,c]+xr[dst,h,c]); segment max
// 16 lanes per edge; lane l handles feature idx l*8..l*8+7 (one head h=l>>2)
__global__ __launch_bounds__(256) void edge_logits(
    const float* __restrict__ XL, const float* __restrict__ XR,
    const float* __restrict__ att, const int* __restrict__ edge,
    float* __restrict__ ebuf, unsigned* __restrict__ menc) {
  int t = blockIdx.x * 256 + threadIdx.x;
  int eid = t >> 4, l = t & 15;
  int src = edge[eid], dst = edge[NE + eid];
  const float* pl = XL + (size_t)src * PD + l * 8;
  const float* pr = XR + (size_t)dst * PD + l * 8;
  const float* pa = att + l * 8;
  float s = 0.f;
#pragma unroll
  for (int j = 0; j < 8; ++j) {
    float z = pl[j] + pr[j];
    float g = z > 0.f ? z : 0.2f * z;
    s += pa[j] * g;
  }
  s += __shfl_xor(s, 1);
  s += __shfl_xor(s, 2);
  if ((l & 3) == 0) {
    int h = l >> 2;
    ebuf[(size_t)eid * 4 + h] = s;
    atomicMax(menc + (size_t)dst * 4 + h, encf(s));
  }
}

// pass 2: ex = exp(e - m[dst]); segment sum. 1 thread per (edge, head)
__global__ __launch_bounds__(256) void edge_exp(
    const int* __restrict__ edge, float* __restrict__ ebuf,
    const unsigned* __restrict__ menc, float* __restrict__ den) {
  int i = blockIdx.x * 256 + threadIdx.x;
  int eid = i >> 2, h = i & 3;
  int dst = edge[NE + eid];
  float m = decf(menc[dst * 4 + h]);
  float ex = __expf(ebuf[i] - m);
  ebuf[i] = ex;
  atomicAdd(den + dst * 4 + h, ex);
}

// pass 3: accum[dst] += alpha * xl[src]; 16 lanes/edge, 8 atomics/lane
__global__ __launch_bounds__(256) void edge_aggr(
    const float* __restrict__ XL, const int* __restrict__ edge,
    const float* __restrict__ ebuf, const float* __restrict__ den,
    float* __restrict__ accum) {
  int t = blockIdx.x * 256 + threadIdx.x;
  int eid = t >> 4, l = t & 15;
  int src = edge[eid], dst = edge[NE + eid];
  int h = l >> 2;
  float alpha = ebuf[(size_t)eid * 4 + h] / (den[dst * 4 + h] + 1e-16f);
  const float* pl = XL + (size_t)src * PD + l * 8;
  float* pd = accum + (size_t)dst * PD + l * 8;
#pragma unroll
  for (int j = 0; j < 8; ++j) atomicAdd(pd + j, alpha * pl[j]);
}

// out = elu(accum + b_gat), fp32
__global__ __launch_bounds__(256) void finalize(
    const float* __restrict__ accum, const float* __restrict__ bg,
    float* __restrict__ out) {
  int i = blockIdx.x * 256 + threadIdx.x;
  float v = accum[i] + bg[i & 127];
  v = v > 0.f ? v : expm1f(v);
  out[i] = v;
}

// ---------------------------------------------------------------------------
extern "C" void kernel_launch(void* const* d_in, const int* in_sizes, int n_in,
                              void* d_out, int out_size, void* d_ws, size_t ws_size,
                              hipStream_t stream) {
  const float* x1  = (const float*)d_in[0];   // [25000,2000]
  const float* x2  = (const float*)d_in[1];   // [25000,500]
  const float* Wp1 = (const float*)d_in[2];   // [2000,128]
  const float* bp1 = (const float*)d_in[3];   // [128]
  const float* Wp2 = (const float*)d_in[4];   // [500,128]
  const float* bp2 = (const float*)d_in[5];   // [128]
  const float* Wl  = (const float*)d_in[6];   // [128,128]
  const float* Wr  = (const float*)d_in[7];   // [128,128]
  const float* att = (const float*)d_in[8];   // [4,32] flat [128]
  const float* bg  = (const float*)d_in[9];   // [128]
  const int*   edge = (const int*)d_in[10];   // [2,800000]

  // workspace layout (65.6 MB), with aliasing:
  //   region0 @0:          12.8MB  X (bf16, dead after gemm3/4) -> ebuf (fp32 [NE,4])
  //   region1 @12.8M:      25.6MB  XL (fp32 [NN,128])
  //   region2 @38.4M:      25.6MB  XR (fp32, dead after logits) -> accum (fp32)
  //   @64.0M: menc 800KB;  @64.8M: den 800KB
  char* ws = (char*)d_ws;
  unsigned short* X    = (unsigned short*)(ws);
  float*          ebuf = (float*)(ws);
  float*          XL   = (float*)(ws + 12800000);
  float*          XR   = (float*)(ws + 38400000);
  float*          accum = (float*)(ws + 38400000);
  unsigned*       menc = (unsigned*)(ws + 64000000);
  float*          den  = (float*)(ws + 64800000);

  init_md<<<(NN * 4 + 255) / 256, 256, 0, stream>>>(den, menc);

  gemm_k<1, 0><<<(25000 + 63) / 64, 256, 0, stream>>>(x1, Wp1, bp1, X, 25000, 2000);
  gemm_k<1, 0><<<(25000 + 63) / 64, 256, 0, stream>>>(x2, Wp2, bp2,
                                                      X + (size_t)25000 * PD, 25000, 500);
  gemm_k<0, 1><<<(NN + 63) / 64, 256, 0, stream>>>(X, Wl, nullptr, XL, NN, PD);
  gemm_k<0, 1><<<(NN + 63) / 64, 256, 0, stream>>>(X, Wr, nullptr, XR, NN, PD);

  edge_logits<<<NE / 16, 256, 0, stream>>>(XL, XR, att, edge, ebuf, menc);
  init_accum<<<NN * PD / 256, 256, 0, stream>>>(accum);   // overwrites XR (dead)
  edge_exp<<<NE * 4 / 256, 256, 0, stream>>>(edge, ebuf, menc, den);
  edge_aggr<<<NE / 16, 256, 0, stream>>>(XL, edge, ebuf, den, accum);
  finalize<<<NN * PD / 256, 256, 0, stream>>>(accum, bg, (float*)d_out);
}

// Round 3
// 807.208 us; speedup vs baseline: 4.4460x; 4.4460x over previous
//
#include <hip/hip_runtime.h>

#define NN 50000
#define NE 800000
#define PD 128
#define NBLK 196   // ceil(NN/256)

typedef __attribute__((ext_vector_type(8))) short bf16x8;
typedef __attribute__((ext_vector_type(4))) float f32x4;

__device__ __forceinline__ float bf2f(unsigned short h) {
  union { unsigned u; float f; } v; v.u = ((unsigned)h) << 16; return v.f;
}
__device__ __forceinline__ unsigned short f2bf(float f) {
  union { float f; unsigned u; } v; v.f = f;
  unsigned r = (v.u + 0x7FFFu + ((v.u >> 16) & 1u)) >> 16;
  return (unsigned short)r;
}

// ---------------------------------------------------------------------------
// C[M,128] = A[M,K] @ B[K,128] (+ bias). A: fp32 (A_F32=1) or bf16; B/bias fp32.
// Out: fp32 (OUT_F32=1) or bf16. MFMA 16x16x32 bf16, fp32 accumulate.
template <int A_F32, int OUT_F32>
__global__ __launch_bounds__(256) void gemm_k(
    const void* __restrict__ Av, const float* __restrict__ B,
    const float* __restrict__ bias, void* __restrict__ Cv, int M, int K) {
  __shared__ __align__(16) unsigned short As[64 * 40];
  __shared__ __align__(16) unsigned short Bs[32 * 132];
  int tid = threadIdx.x;
  int wave = tid >> 6, lane = tid & 63;
  int m16 = lane & 15, quad = lane >> 4;
  int row0 = blockIdx.x * 64;

  f32x4 acc[8];
#pragma unroll
  for (int t = 0; t < 8; ++t) acc[t] = (f32x4){0.f, 0.f, 0.f, 0.f};

  int nchunks = (K + 31) / 32;
  for (int ch = 0; ch < nchunks; ++ch) {
    int k0 = ch * 32;
    for (int s = tid; s < 512; s += 256) {
      int r = s >> 3, c4 = s & 7;
      int gr = row0 + r, gk = k0 + c4 * 4;
      ushort4 v = {0, 0, 0, 0};
      if (gr < M && gk < K) {
        if (A_F32) {
          const float* A = (const float*)Av;
          float4 f = *(const float4*)(A + (size_t)gr * K + gk);
          v.x = f2bf(f.x); v.y = f2bf(f.y); v.z = f2bf(f.z); v.w = f2bf(f.w);
        } else {
          const unsigned short* A = (const unsigned short*)Av;
          v = *(const ushort4*)(A + (size_t)gr * K + gk);
        }
      }
      *(ushort4*)(As + r * 40 + c4 * 4) = v;
    }
    for (int s = tid; s < 1024; s += 256) {
      int kk = s >> 5, c4 = s & 31;
      int gk = k0 + kk;
      ushort4 v = {0, 0, 0, 0};
      if (gk < K) {
        float4 f = *(const float4*)(B + (size_t)gk * PD + c4 * 4);
        v.x = f2bf(f.x); v.y = f2bf(f.y); v.z = f2bf(f.z); v.w = f2bf(f.w);
      }
      *(ushort4*)(Bs + kk * 132 + c4 * 4) = v;
    }
    __syncthreads();

    bf16x8 a = *(const bf16x8*)(As + (wave * 16 + m16) * 40 + quad * 8);
#pragma unroll
    for (int t = 0; t < 8; ++t) {
      bf16x8 b;
#pragma unroll
      for (int j = 0; j < 8; ++j)
        b[j] = (short)Bs[(quad * 8 + j) * 132 + t * 16 + m16];
      acc[t] = __builtin_amdgcn_mfma_f32_16x16x32_bf16(a, b, acc[t], 0, 0, 0);
    }
    __syncthreads();
  }

#pragma unroll
  for (int t = 0; t < 8; ++t) {
    int col = t * 16 + m16;
    float bv = bias ? bias[col] : 0.f;
#pragma unroll
    for (int r = 0; r < 4; ++r) {
      int row = row0 + wave * 16 + quad * 4 + r;
      if (row < M) {
        float v = acc[t][r] + bv;
        if (OUT_F32) ((float*)Cv)[(size_t)row * PD + col] = v;
        else ((unsigned short*)Cv)[(size_t)row * PD + col] = f2bf(v);
      }
    }
  }
}

// ---------------------------------------------------------------------------
// CSR build: histogram -> 2-level exclusive scan -> scatter
__global__ __launch_bounds__(256) void zero_deg(int* __restrict__ deg) {
  int i = blockIdx.x * 256 + threadIdx.x;
  if (i < NN) deg[i] = 0;
}

__global__ __launch_bounds__(256) void hist(const int* __restrict__ edge,
                                            int* __restrict__ deg) {
  int i = blockIdx.x * 256 + threadIdx.x;
  if (i < NE) atomicAdd(&deg[edge[NE + i]], 1);
}

// per-256-block sums
__global__ __launch_bounds__(256) void scan1(const int* __restrict__ deg,
                                             int* __restrict__ bsum) {
  __shared__ int sd[256];
  int i = blockIdx.x * 256 + threadIdx.x;
  sd[threadIdx.x] = (i < NN) ? deg[i] : 0;
  __syncthreads();
  for (int off = 128; off > 0; off >>= 1) {
    if (threadIdx.x < off) sd[threadIdx.x] += sd[threadIdx.x + off];
    __syncthreads();
  }
  if (threadIdx.x == 0) bsum[blockIdx.x] = sd[0];
}

// exclusive scan of NBLK partials (serial, tiny)
__global__ __launch_bounds__(64) void scan2(const int* __restrict__ bsum,
                                            int* __restrict__ boff) {
  if (threadIdx.x == 0) {
    int run = 0;
    for (int b = 0; b < NBLK; ++b) { boff[b] = run; run += bsum[b]; }
  }
}

// per-element exclusive scan: start[i], cursor[i]; start[NN]=NE
__global__ __launch_bounds__(256) void scan3(const int* __restrict__ deg,
                                             const int* __restrict__ boff,
                                             int* __restrict__ start,
                                             int* __restrict__ cursor) {
  __shared__ int sd[256];
  int i = blockIdx.x * 256 + threadIdx.x;
  int v = (i < NN) ? deg[i] : 0;
  sd[threadIdx.x] = v;
  __syncthreads();
  // Hillis-Steele inclusive scan
  for (int off = 1; off < 256; off <<= 1) {
    int t = (threadIdx.x >= off) ? sd[threadIdx.x - off] : 0;
    __syncthreads();
    sd[threadIdx.x] += t;
    __syncthreads();
  }
  if (i < NN) {
    int excl = boff[blockIdx.x] + sd[threadIdx.x] - v;
    start[i] = excl;
    cursor[i] = excl;
  }
  if (blockIdx.x == 0 && threadIdx.x == 0) start[NN] = NE;
}

__global__ __launch_bounds__(256) void scatter(const int* __restrict__ edge,
                                               int* __restrict__ cursor,
                                               int* __restrict__ esrc) {
  int i = blockIdx.x * 256 + threadIdx.x;
  if (i < NE) {
    int dst = edge[NE + i];
    int pos = atomicAdd(&cursor[dst], 1);
    esrc[pos] = edge[i];
  }
}

// ---------------------------------------------------------------------------
// Fused GATv2: one wave per dst node. Online softmax over incoming edges.
// Lane layout: h = lane>>4 (head), i = lane&15; features f0 = lane*2, f0+1.
// Logit: 16-lane shuffle reduction within head group. No atomics anywhere.
__global__ __launch_bounds__(256) void gat_fused(
    const unsigned short* __restrict__ XLb,   // [NN,128] bf16 (values+source side)
    const float* __restrict__ XR,             // [NN,128] fp32 (target side)
    const float* __restrict__ att,            // [128] = [H*C]
    const float* __restrict__ bg,             // [128]
    const int* __restrict__ start,            // [NN+1]
    const int* __restrict__ esrc,             // [NE] src ids sorted by dst
    float* __restrict__ out) {                // [NN,128]
  int wave = threadIdx.x >> 6, lane = threadIdx.x & 63;
  int d = blockIdx.x * 4 + wave;
  int f0 = lane * 2;

  float2 xr = *(const float2*)(XR + (size_t)d * PD + f0);
  float a0c = att[f0], a1c = att[f0 + 1];

  int s = start[d], e_end = start[d + 1];

  float m = -INFINITY, l = 0.f, acc0 = 0.f, acc1 = 0.f;
  for (int j = s; j < e_end; ++j) {
    int src = esrc[j];
    unsigned xlu = *(const unsigned*)(XLb + (size_t)src * PD + f0);
    float xl0 = bf2f((unsigned short)(xlu & 0xFFFFu));
    float xl1 = bf2f((unsigned short)(xlu >> 16));
    float z0 = xl0 + xr.x, z1 = xl1 + xr.y;
    float g0 = z0 > 0.f ? z0 : 0.2f * z0;
    float g1 = z1 > 0.f ? z1 : 0.2f * z1;
    float t = a0c * g0 + a1c * g1;
    // reduce across the 16 lanes of this head
    t += __shfl_xor(t, 1);
    t += __shfl_xor(t, 2);
    t += __shfl_xor(t, 4);
    t += __shfl_xor(t, 8);
    // online softmax update
    float mn = fmaxf(m, t);
    float c = __expf(m - mn);   // 0 when m=-inf
    float p = __expf(t - mn);
    l = l * c + p;
    acc0 = acc0 * c + p * xl0;
    acc1 = acc1 * c + p * xl1;
    m = mn;
  }

  float inv = 1.f / (l + 1e-16f);
  float v0 = acc0 * inv + bg[f0];
  float v1 = acc1 * inv + bg[f0 + 1];
  v0 = v0 > 0.f ? v0 : expm1f(v0);
  v1 = v1 > 0.f ? v1 : expm1f(v1);
  *(float2*)(out + (size_t)d * PD + f0) = make_float2(v0, v1);
}

// ---------------------------------------------------------------------------
extern "C" void kernel_launch(void* const* d_in, const int* in_sizes, int n_in,
                              void* d_out, int out_size, void* d_ws, size_t ws_size,
                              hipStream_t stream) {
  const float* x1  = (const float*)d_in[0];   // [25000,2000]
  const float* x2  = (const float*)d_in[1];   // [25000,500]
  const float* Wp1 = (const float*)d_in[2];   // [2000,128]
  const float* bp1 = (const float*)d_in[3];   // [128]
  const float* Wp2 = (const float*)d_in[4];   // [500,128]
  const float* bp2 = (const float*)d_in[5];   // [128]
  const float* Wl  = (const float*)d_in[6];   // [128,128]
  const float* Wr  = (const float*)d_in[7];   // [128,128]
  const float* att = (const float*)d_in[8];   // [128]
  const float* bg  = (const float*)d_in[9];   // [128]
  const int*   edge = (const int*)d_in[10];   // [2,800000]

  // workspace layout (~55 MB):
  //   @0:      X    bf16 [NN,128]  12.8 MB
  //   @12.8M:  XLb  bf16 [NN,128]  12.8 MB
  //   @25.6M:  XR   fp32 [NN,128]  25.6 MB
  //   @51.2M:  esrc int  [NE]       3.2 MB
  //   @54.4M:  start int [NN+1]
  //   @54.7M:  cursor int [NN]  (aliases deg: deg dead after scan3)
  //   @55.0M:  deg int [NN]
  //   @55.3M:  bsum/boff int [NBLK] each
  char* ws = (char*)d_ws;
  unsigned short* X    = (unsigned short*)(ws);
  unsigned short* XLb  = (unsigned short*)(ws + 12800000);
  float*          XR   = (float*)(ws + 25600000);
  int*            esrc = (int*)(ws + 51200000);
  int*            start = (int*)(ws + 54400000);
  int*            cursor = (int*)(ws + 54700000);
  int*            deg  = (int*)(ws + 55000000);
  int*            bsum = (int*)(ws + 55300000);
  int*            boff = (int*)(ws + 55310000);

  // --- CSR build (independent of GEMMs) ---
  zero_deg<<<NBLK, 256, 0, stream>>>(deg);
  hist<<<(NE + 255) / 256, 256, 0, stream>>>(edge, deg);
  scan1<<<NBLK, 256, 0, stream>>>(deg, bsum);
  scan2<<<1, 64, 0, stream>>>(bsum, boff);
  scan3<<<NBLK, 256, 0, stream>>>(deg, boff, start, cursor);
  scatter<<<(NE + 255) / 256, 256, 0, stream>>>(edge, cursor, esrc);

  // --- projections + GAT linear transforms ---
  gemm_k<1, 0><<<(25000 + 63) / 64, 256, 0, stream>>>(x1, Wp1, bp1, X, 25000, 2000);
  gemm_k<1, 0><<<(25000 + 63) / 64, 256, 0, stream>>>(x2, Wp2, bp2,
                                                      X + (size_t)25000 * PD, 25000, 500);
  gemm_k<0, 0><<<(NN + 63) / 64, 256, 0, stream>>>(X, Wl, nullptr, XLb, NN, PD);
  gemm_k<0, 1><<<(NN + 63) / 64, 256, 0, stream>>>(X, Wr, nullptr, XR, NN, PD);

  // --- fused attention + aggregation + ELU ---
  gat_fused<<<NN / 4, 256, 0, stream>>>(XLb, XR, att, bg, start, esrc,
                                        (float*)d_out);
}

// Round 4
// 694.149 us; speedup vs baseline: 5.1701x; 1.1629x over previous
//
#include <hip/hip_runtime.h>

#define NN 50000
#define NE 800000
#define PD 128
#define NBLK 196       // ceil(NN/256)
#define GB1 391        // ceil(25000/64) blocks for input1
#define M_HALF 25000

typedef __attribute__((ext_vector_type(8))) short bf16x8;
typedef __attribute__((ext_vector_type(4))) float f32x4;

__device__ __forceinline__ float bf2f(unsigned short h) {
  union { unsigned u; float f; } v; v.u = ((unsigned)h) << 16; return v.f;
}
__device__ __forceinline__ unsigned short f2bf(float f) {
  union { float f; unsigned u; } v; v.f = f;
  unsigned r = (v.u + 0x7FFFu + ((v.u >> 16) & 1u)) >> 16;
  return (unsigned short)r;
}
__device__ __forceinline__ unsigned pack2(float a, float b) {
  return (unsigned)f2bf(a) | ((unsigned)f2bf(b) << 16);
}

// ---------------------------------------------------------------------------
// Composite weights: Wct1[n][k] = bf16( sum_p Wp1[k][p]*WLR[p][n] ), n in [0,256)
// (WLR = [Wl | Wr]); pre-transposed [n][k] with zero-padded K (2048 / 512).
// biasc[0..255] = bp1 @ WLR ; biasc[256..511] = bp2 @ WLR.
__global__ __launch_bounds__(256) void wtrans(
    const float* __restrict__ Wp1, const float* __restrict__ Wp2,
    const float* __restrict__ Wl, const float* __restrict__ Wr,
    const float* __restrict__ bp1, const float* __restrict__ bp2,
    unsigned short* __restrict__ Wct1, unsigned short* __restrict__ Wct2,
    float* __restrict__ biasc) {
  int b = blockIdx.x, n = threadIdx.x;
  __shared__ float arow[128];
  const float* W = (n < 128) ? Wl : Wr;
  int nc = n & 127;
  if (b < 2048) {
    int k = b;
    unsigned short v = 0;
    if (k < 2000) {
      if (n < 128) arow[n] = Wp1[k * 128 + n];
      __syncthreads();
      float s = 0.f;
      for (int p = 0; p < 128; ++p) s += arow[p] * W[p * 128 + nc];
      v = f2bf(s);
    }
    Wct1[(size_t)n * 2048 + k] = v;
  } else if (b < 2560) {
    int k = b - 2048;
    unsigned short v = 0;
    if (k < 500) {
      if (n < 128) arow[n] = Wp2[k * 128 + n];
      __syncthreads();
      float s = 0.f;
      for (int p = 0; p < 128; ++p) s += arow[p] * W[p * 128 + nc];
      v = f2bf(s);
    }
    Wct2[(size_t)n * 512 + k] = v;
  } else {
    float s1 = 0.f, s2 = 0.f;
    for (int p = 0; p < 128; ++p) {
      float w = W[p * 128 + nc];
      s1 += bp1[p] * w;
      s2 += bp2[p] * w;
    }
    biasc[n] = s1;
    biasc[256 + n] = s2;
  }
}

// ---------------------------------------------------------------------------
// One fused GEMM: rows 0..24999 = x1 @ Wc1 (K=2000), rows 25000.. = x2 @ Wc2
// (K=500). Tile 64(M) x 256(N), K-chunk 32, double-buffered LDS, all fragment
// loads ds_read_b128. Cols 0..127 -> XLb (bf16, +biasL), 128..255 -> XR (fp32).
__global__ __launch_bounds__(256) void big_gemm(
    const float* __restrict__ x1, const float* __restrict__ x2,
    const unsigned short* __restrict__ Wct1, const unsigned short* __restrict__ Wct2,
    const float* __restrict__ biasc,
    unsigned short* __restrict__ XLb, float* __restrict__ XR) {
  // per buffer: As 64x40 u16 (5120B) + Bs 256x40 u16 (20480B) = 25600B; x2 buffers
  __shared__ __align__(16) unsigned short lds[2 * 12800];
  int tid = threadIdx.x;
  int wave = tid >> 6, lane = tid & 63;
  int m16 = lane & 15, quad = lane >> 4;

  int inp = (blockIdx.x >= GB1) ? 1 : 0;
  int blk = inp ? (blockIdx.x - GB1) : blockIdx.x;
  const float* A = inp ? x2 : x1;
  const unsigned short* Wct = inp ? Wct2 : Wct1;
  const int K = inp ? 500 : 2000;
  const int bstr = inp ? 512 : 2048;   // Wct row stride in u16 (zero-padded)
  const int nch = (K + 31) / 32;
  int row0 = blk * 64;

  // staging mapping: A granule = (row ar, 8 k's at ako); 256 granules, 1/thread
  int ar = tid >> 2, ako = (tid & 3) << 3;
  bool arow_ok = (row0 + ar) < M_HALF;
  const float* aptr = A + (size_t)(row0 + ar) * K + ako;
  // B granules: 1024 of 8 u16 (256 n x 4 octets), 4/thread
  int bn0 = tid >> 2, bko = (tid & 3) << 3;

  f32x4 acc[16];
#pragma unroll
  for (int t = 0; t < 16; ++t) acc[t] = (f32x4){0.f, 0.f, 0.f, 0.f};

  float4 pa0, pa1;
  uint4 pb[4];

#define LOADCH(ch)                                                         \
  {                                                                        \
    int k0 = (ch) * 32;                                                    \
    if (arow_ok) {                                                         \
      pa0 = *(const float4*)(aptr + k0);                                   \
      pa1 = *(const float4*)(aptr + k0 + 4);                               \
    }                                                                      \
    const unsigned short* bp_ = Wct + k0 + bko;                            \
    _Pragma("unroll") for (int i = 0; i < 4; ++i)                          \
        pb[i] = *(const uint4*)(bp_ + (size_t)(bn0 + i * 64) * bstr);      \
  }

#define STORECH(buf)                                                       \
  {                                                                        \
    unsigned short* As_ = lds + (buf) * 12800;                             \
    unsigned short* Bs_ = As_ + 2560;                                      \
    uint4 wA;                                                              \
    if (arow_ok) {                                                         \
      wA.x = pack2(pa0.x, pa0.y); wA.y = pack2(pa0.z, pa0.w);              \
      wA.z = pack2(pa1.x, pa1.y); wA.w = pack2(pa1.z, pa1.w);              \
    } else { wA.x = wA.y = wA.z = wA.w = 0u; }                             \
    *(uint4*)(As_ + ar * 40 + ako) = wA;                                   \
    _Pragma("unroll") for (int i = 0; i < 4; ++i)                          \
        *(uint4*)(Bs_ + (bn0 + i * 64) * 40 + bko) = pb[i];                \
  }

  LOADCH(0);
  STORECH(0);
  __syncthreads();

  for (int ch = 0; ch < nch; ++ch) {
    int cur = ch & 1;
    if (ch + 1 < nch) LOADCH(ch + 1);
    {
      const unsigned short* As_ = lds + cur * 12800;
      const unsigned short* Bs_ = As_ + 2560;
      bf16x8 a = *(const bf16x8*)(As_ + (wave * 16 + m16) * 40 + quad * 8);
#pragma unroll
      for (int t = 0; t < 16; ++t) {
        bf16x8 b = *(const bf16x8*)(Bs_ + (t * 16 + m16) * 40 + quad * 8);
        acc[t] = __builtin_amdgcn_mfma_f32_16x16x32_bf16(a, b, acc[t], 0, 0, 0);
      }
    }
    if (ch + 1 < nch) STORECH(cur ^ 1);
    __syncthreads();
  }

  // epilogue: C/D layout col=lane&15 (within 16-tile), row=quad*4+r
  const float* bc = biasc + inp * 256;
  int rbase = row0 + wave * 16 + quad * 4;
  size_t growbase = (size_t)inp * M_HALF + rbase;
#pragma unroll
  for (int t = 0; t < 16; ++t) {
    int c = t * 16 + m16;
    float bv = bc[c];
#pragma unroll
    for (int r = 0; r < 4; ++r) {
      if (rbase + r < M_HALF) {
        size_t row = growbase + r;
        float v = acc[t][r] + bv;
        if (c < PD) XLb[row * PD + c] = f2bf(v);
        else XR[row * PD + (c - PD)] = v;
      }
    }
  }
#undef LOADCH
#undef STORECH
}

// ---------------------------------------------------------------------------
// CSR build: histogram -> 2-level exclusive scan -> scatter
__global__ __launch_bounds__(256) void zero_deg(int* __restrict__ deg) {
  int i = blockIdx.x * 256 + threadIdx.x;
  if (i < NN) deg[i] = 0;
}

__global__ __launch_bounds__(256) void hist(const int* __restrict__ edge,
                                            int* __restrict__ deg) {
  int i = blockIdx.x * 256 + threadIdx.x;
  if (i < NE) atomicAdd(&deg[edge[NE + i]], 1);
}

__global__ __launch_bounds__(256) void scan1(const int* __restrict__ deg,
                                             int* __restrict__ bsum) {
  __shared__ int sd[256];
  int i = blockIdx.x * 256 + threadIdx.x;
  sd[threadIdx.x] = (i < NN) ? deg[i] : 0;
  __syncthreads();
  for (int off = 128; off > 0; off >>= 1) {
    if (threadIdx.x < off) sd[threadIdx.x] += sd[threadIdx.x + off];
    __syncthreads();
  }
  if (threadIdx.x == 0) bsum[blockIdx.x] = sd[0];
}

__global__ __launch_bounds__(64) void scan2(const int* __restrict__ bsum,
                                            int* __restrict__ boff) {
  if (threadIdx.x == 0) {
    int run = 0;
    for (int b = 0; b < NBLK; ++b) { boff[b] = run; run += bsum[b]; }
  }
}

__global__ __launch_bounds__(256) void scan3(const int* __restrict__ deg,
                                             const int* __restrict__ boff,
                                             int* __restrict__ start,
                                             int* __restrict__ cursor) {
  __shared__ int sd[256];
  int i = blockIdx.x * 256 + threadIdx.x;
  int v = (i < NN) ? deg[i] : 0;
  sd[threadIdx.x] = v;
  __syncthreads();
  for (int off = 1; off < 256; off <<= 1) {
    int t = (threadIdx.x >= off) ? sd[threadIdx.x - off] : 0;
    __syncthreads();
    sd[threadIdx.x] += t;
    __syncthreads();
  }
  if (i < NN) {
    int excl = boff[blockIdx.x] + sd[threadIdx.x] - v;
    start[i] = excl;
    cursor[i] = excl;
  }
  if (blockIdx.x == 0 && threadIdx.x == 0) start[NN] = NE;
}

__global__ __launch_bounds__(256) void scatter(const int* __restrict__ edge,
                                               int* __restrict__ cursor,
                                               int* __restrict__ esrc) {
  int i = blockIdx.x * 256 + threadIdx.x;
  if (i < NE) {
    int dst = edge[NE + i];
    int pos = atomicAdd(&cursor[dst], 1);
    esrc[pos] = edge[i];
  }
}

// ---------------------------------------------------------------------------
// Fused GATv2: one wave per dst node, online softmax, no atomics.
// Lane l: head h = l>>4; features f0 = 2l, 2l+1.
__global__ __launch_bounds__(256) void gat_fused(
    const unsigned short* __restrict__ XLb, const float* __restrict__ XR,
    const float* __restrict__ att, const float* __restrict__ bg,
    const int* __restrict__ start, const int* __restrict__ esrc,
    float* __restrict__ out) {
  int wave = threadIdx.x >> 6, lane = threadIdx.x & 63;
  int d = blockIdx.x * 4 + wave;
  int f0 = lane * 2;

  float2 xr = *(const float2*)(XR + (size_t)d * PD + f0);
  float a0c = att[f0], a1c = att[f0 + 1];

  int s = start[d], e_end = start[d + 1];

  float m = -INFINITY, l = 0.f, acc0 = 0.f, acc1 = 0.f;
  for (int j = s; j < e_end; ++j) {
    int src = esrc[j];
    unsigned xlu = *(const unsigned*)(XLb + (size_t)src * PD + f0);
    float xl0 = bf2f((unsigned short)(xlu & 0xFFFFu));
    float xl1 = bf2f((unsigned short)(xlu >> 16));
    float z0 = xl0 + xr.x, z1 = xl1 + xr.y;
    float g0 = z0 > 0.f ? z0 : 0.2f * z0;
    float g1 = z1 > 0.f ? z1 : 0.2f * z1;
    float t = a0c * g0 + a1c * g1;
    t += __shfl_xor(t, 1);
    t += __shfl_xor(t, 2);
    t += __shfl_xor(t, 4);
    t += __shfl_xor(t, 8);
    float mn = fmaxf(m, t);
    float c = __expf(m - mn);
    float p = __expf(t - mn);
    l = l * c + p;
    acc0 = acc0 * c + p * xl0;
    acc1 = acc1 * c + p * xl1;
    m = mn;
  }

  float inv = 1.f / (l + 1e-16f);
  float v0 = acc0 * inv + bg[f0];
  float v1 = acc1 * inv + bg[f0 + 1];
  v0 = v0 > 0.f ? v0 : expm1f(v0);
  v1 = v1 > 0.f ? v1 : expm1f(v1);
  *(float2*)(out + (size_t)d * PD + f0) = make_float2(v0, v1);
}

// ---------------------------------------------------------------------------
extern "C" void kernel_launch(void* const* d_in, const int* in_sizes, int n_in,
                              void* d_out, int out_size, void* d_ws, size_t ws_size,
                              hipStream_t stream) {
  const float* x1  = (const float*)d_in[0];
  const float* x2  = (const float*)d_in[1];
  const float* Wp1 = (const float*)d_in[2];
  const float* bp1 = (const float*)d_in[3];
  const float* Wp2 = (const float*)d_in[4];
  const float* bp2 = (const float*)d_in[5];
  const float* Wl  = (const float*)d_in[6];
  const float* Wr  = (const float*)d_in[7];
  const float* att = (const float*)d_in[8];
  const float* bg  = (const float*)d_in[9];
  const int*   edge = (const int*)d_in[10];

  // workspace (~43.5 MB)
  char* ws = (char*)d_ws;
  unsigned short* XLb   = (unsigned short*)(ws);               // 12.8 MB
  float*          XR    = (float*)(ws + 12800000);             // 25.6 MB
  int*            esrc  = (int*)(ws + 38400000);               // 3.2 MB
  int*            start = (int*)(ws + 41600000);               // (NN+1)*4
  int*            cursor = (int*)(ws + 41800192);
  int*            deg   = (int*)(ws + 42000384);
  int*            bsum  = (int*)(ws + 42200576);
  int*            boff  = (int*)(ws + 42201600);
  unsigned short* Wct1  = (unsigned short*)(ws + 42202624);    // 1 MB [256][2048]
  unsigned short* Wct2  = (unsigned short*)(ws + 43251200);    // 256 KB [256][512]
  float*          biasc = (float*)(ws + 43513344);             // [2][256]

  // composite weights (independent, tiny)
  wtrans<<<2561, 256, 0, stream>>>(Wp1, Wp2, Wl, Wr, bp1, bp2, Wct1, Wct2, biasc);

  // CSR build
  zero_deg<<<NBLK, 256, 0, stream>>>(deg);
  hist<<<(NE + 255) / 256, 256, 0, stream>>>(edge, deg);
  scan1<<<NBLK, 256, 0, stream>>>(deg, bsum);
  scan2<<<1, 64, 0, stream>>>(bsum, boff);
  scan3<<<NBLK, 256, 0, stream>>>(deg, boff, start, cursor);
  scatter<<<(NE + 255) / 256, 256, 0, stream>>>(edge, cursor, esrc);

  // one fused GEMM producing XLb (bf16) and XR (fp32)
  big_gemm<<<GB1 * 2, 256, 0, stream>>>(x1, x2, Wct1, Wct2, biasc, XLb, XR);

  // fused attention + aggregation + ELU
  gat_fused<<<NN / 4, 256, 0, stream>>>(XLb, XR, att, bg, start, esrc,
                                        (float*)d_out);
}